// Round 7
// baseline (67.249 us; speedup 1.0000x reference)
//
#include <hip/hip_runtime.h>
#include <hip/hip_bf16.h>

#define B_ 32
#define L_ 512
#define H_ 1024
#define E_ 8
#define R_ 16

typedef float f32x4 __attribute__((ext_vector_type(4)));
typedef __bf16 bf16x8 __attribute__((ext_vector_type(8)));

static __device__ __forceinline__ __bf16 f2b(float f) { return (__bf16)f; }

// Fully wave-independent design. Per 64-lane wave: one 16-row tile of one b.
//   Phase A (swapped operands): acc = mfma(Wfrag, Xfrag, acc) over K=1024
//     -> lane ends holding D[l=lane&15][p=4*(lane>>4)+j]  == EXACTLY the
//        B-fragment layout phase B needs. No reduce, no transpose, no LDS.
//   Pack: dfrag[j] = bf16(acc0[j]*g0), dfrag[4+j] = bf16(acc1[j]*g1).
//   Phase B: out^T-tile MFMAs over 64 column groups, C-init = exact f32
//     residual loaded from this wave's own rows (L1/L2-hot).
// Gates: computed once per block in a tiny prologue (2 barriers at start,
// zero inter-wave coupling afterwards).
__global__ __launch_bounds__(256) void moe_fused_kernel(
    const float* __restrict__ x, const float* __restrict__ rw,
    const float* __restrict__ ldown, const float* __restrict__ lup,
    float* __restrict__ out)
{
  __shared__ float logits[E_];
  __shared__ float gv[2];
  __shared__ int   ge[2];

  const int t    = threadIdx.x;
  const int w    = t >> 6;
  const int lane = t & 63;
  const int gq   = lane >> 4;               // 0..3
  const int r16  = lane & 15;

  const int tile = blockIdx.x * 4 + w;      // 1024 wave-tiles total
  const int b    = tile >> 5;               // uniform across the block
  const int l0   = (tile & 31) * 16;

  // ---- gates prologue (per-block redundant; reads are L2/L3-hot) ----------
  {
    const int e = t >> 5, s = t & 31;
    const float* cls = x + (size_t)b * L_ * H_;   // x[b,0,:]
    const float* wr  = rw + (size_t)e * H_;
    float p = 0.f;
#pragma unroll
    for (int c = s; c < 256; c += 32) {
      float4 xv = *(const float4*)(cls + 4 * c);
      float4 wv = *(const float4*)(wr + 4 * c);
      p += xv.x * wv.x + xv.y * wv.y + xv.z * wv.z + xv.w * wv.w;
    }
#pragma unroll
    for (int off = 16; off; off >>= 1) p += __shfl_down(p, off, 32);
    if (s == 0) logits[e] = p;
  }
  __syncthreads();
  if (t == 0) {
    float m0 = -1e30f; int i0 = 0;
    for (int j = 0; j < E_; ++j) if (logits[j] > m0) { m0 = logits[j]; i0 = j; }
    float m1 = -1e30f; int i1 = 0;
    for (int j = 0; j < E_; ++j) if (j != i0 && logits[j] > m1) { m1 = logits[j]; i1 = j; }
    float eb = expf(m1 - m0), inv = 1.f / (1.f + eb);
    gv[0] = inv; gv[1] = eb * inv; ge[0] = i0; ge[1] = i1;
  }
  __syncthreads();                          // last sync in the kernel

  const float g0 = gv[0], g1 = gv[1];
  const int   e0 = ge[0], e1 = ge[1];

  // lane-fixed row pointers
  const float* xr  = x + ((size_t)b * L_ + l0 + r16) * H_;       // this lane's x row
  const float* w0p = ldown + ((size_t)e0 * R_ + r16) * H_;       // A-frag row = r16
  const float* w1p = ldown + ((size_t)e1 * R_ + r16) * H_;

  // ---- Phase A: D^T = Wd(16xK) * X^T(Kx16) per expert, full K per wave ----
  f32x4 acc0 = {0.f, 0.f, 0.f, 0.f};
  f32x4 acc1 = {0.f, 0.f, 0.f, 0.f};

#pragma unroll 4
  for (int s = 0; s < 32; ++s) {
    const int kl = s * 32 + 4 * gq;         // k of elems 0..3 (elems 4..7: +16)
    float4 xlo = *(const float4*)(xr + kl);
    float4 xhi = *(const float4*)(xr + kl + 16);
    float4 alo = *(const float4*)(w0p + kl);
    float4 ahi = *(const float4*)(w0p + kl + 16);
    float4 blo = *(const float4*)(w1p + kl);
    float4 bhi = *(const float4*)(w1p + kl + 16);
    bf16x8 xf  = { f2b(xlo.x), f2b(xlo.y), f2b(xlo.z), f2b(xlo.w),
                   f2b(xhi.x), f2b(xhi.y), f2b(xhi.z), f2b(xhi.w) };
    bf16x8 wf0 = { f2b(alo.x), f2b(alo.y), f2b(alo.z), f2b(alo.w),
                   f2b(ahi.x), f2b(ahi.y), f2b(ahi.z), f2b(ahi.w) };
    bf16x8 wf1 = { f2b(blo.x), f2b(blo.y), f2b(blo.z), f2b(blo.w),
                   f2b(bhi.x), f2b(bhi.y), f2b(bhi.z), f2b(bhi.w) };
    acc0 = __builtin_amdgcn_mfma_f32_16x16x32_bf16(wf0, xf, acc0, 0, 0, 0);
    acc1 = __builtin_amdgcn_mfma_f32_16x16x32_bf16(wf1, xf, acc1, 0, 0, 0);
  }

  // ---- gate + pack: lane now holds D[l=r16][p=4gq+j] == phase-B B-frag ----
  bf16x8 dfrag;
#pragma unroll
  for (int j = 0; j < 4; ++j) {
    dfrag[j]     = f2b(acc0[j] * g0);       // p = 4gq+j       (k = 4gq+j)
    dfrag[4 + j] = f2b(acc1[j] * g1);       // p = 16+4gq+j    (k = 16+4gq+j)
  }

  // ---- Phase B: out^T[h][l] = x^T + U^T(16x32) Dg^T, 64 col-groups --------
  const float* u0b = lup + (size_t)e0 * H_ * R_;
  const float* u1b = lup + (size_t)e1 * H_ * R_;
  float* outr = out + ((size_t)b * L_ + l0 + r16) * H_;          // lane's out row

#pragma unroll 4
  for (int nt = 0; nt < 64; ++nt) {
    const int ha = nt * 16 + r16;           // A-frag row (h) for this lane
    float4 ulo = *(const float4*)(u0b + (size_t)ha * R_ + 4 * gq);
    float4 uhi = *(const float4*)(u1b + (size_t)ha * R_ + 4 * gq);
    bf16x8 uf = { f2b(ulo.x), f2b(ulo.y), f2b(ulo.z), f2b(ulo.w),
                  f2b(uhi.x), f2b(uhi.y), f2b(uhi.z), f2b(uhi.w) };
    // exact f32 residual at the D-frag positions: row l0+r16, cols nt*16+4gq..+3
    float4 rx = *(const float4*)(xr + nt * 16 + 4 * gq);
    f32x4 acc = { rx.x, rx.y, rx.z, rx.w };
    acc = __builtin_amdgcn_mfma_f32_16x16x32_bf16(uf, dfrag, acc, 0, 0, 0);
    *(float4*)(outr + nt * 16 + 4 * gq) = *(float4*)&acc;
  }
}

extern "C" void kernel_launch(void* const* d_in, const int* in_sizes, int n_in,
                              void* d_out, int out_size, void* d_ws, size_t ws_size,
                              hipStream_t stream) {
  const float* x  = (const float*)d_in[0];
  const float* rw = (const float*)d_in[1];
  const float* ld = (const float*)d_in[2];
  const float* lu = (const float*)d_in[3];
  float* outp = (float*)d_out;

  hipLaunchKernelGGL(moe_fused_kernel, dim3(B_ * (L_ / 16) / 4), dim3(256), 0,
                     stream, x, rw, ld, lu, outp);
}

// Round 8
// 56.974 us; speedup vs baseline: 1.1804x; 1.1804x over previous
//
#include <hip/hip_runtime.h>
#include <hip/hip_bf16.h>

#define B_ 32
#define L_ 512
#define H_ 1024
#define E_ 8
#define R_ 16

typedef float f32x4 __attribute__((ext_vector_type(4)));
typedef __bf16 bf16x8 __attribute__((ext_vector_type(8)));

static __device__ __forceinline__ __bf16 f2b(float f) { return (__bf16)f; }

// One wave (64 threads) per 16-row tile; 1024 single-wave blocks; ZERO LDS,
// ZERO barriers. Phase A keeps all 32 bf16 X-fragments in registers; phase B
// re-uses them as the residual (every residual quad == a phase-A quad), so x
// is read from global exactly once. The 128-VGPR xf array also forces a large
// register budget, letting the fully-unrolled loops keep many loads in flight
// (R7's failure was VGPR=36 -> zero ILP).
__global__ __launch_bounds__(64, 1) void moe_fused_kernel(
    const float* __restrict__ x, const float* __restrict__ rw,
    const float* __restrict__ ldown, const float* __restrict__ lup,
    float* __restrict__ out)
{
  const int lane = threadIdx.x;             // 0..63
  const int gq   = lane >> 4;               // 0..3
  const int r16  = lane & 15;

  const int tile = blockIdx.x;              // 1024 tiles
  const int b    = tile >> 5;
  const int l0   = (tile & 31) * 16;

  // ---- gates: fully in-wave (8-lane group per expert), no LDS ------------
  float g0, g1; int e0, e1;
  {
    const int e = lane >> 3, seg = lane & 7;
    const float* xg = x + (size_t)b * L_ * H_ + seg * 128;   // x[b,0,seg*128:]
    const float* wg = rw + (size_t)e * H_ + seg * 128;
    float p = 0.f;
#pragma unroll
    for (int i = 0; i < 32; ++i) {
      float4 xv = *(const float4*)(xg + 4 * i);
      float4 wv = *(const float4*)(wg + 4 * i);
      p += xv.x * wv.x + xv.y * wv.y + xv.z * wv.z + xv.w * wv.w;
    }
    p += __shfl_xor(p, 1);                  // reduce within 8-lane group
    p += __shfl_xor(p, 2);
    p += __shfl_xor(p, 4);
    float lg[8];
#pragma unroll
    for (int j = 0; j < 8; ++j) lg[j] = __shfl(p, j * 8);
    float m0 = lg[0]; int i0 = 0;
#pragma unroll
    for (int j = 1; j < 8; ++j) if (lg[j] > m0) { m0 = lg[j]; i0 = j; }
    float m1 = -1e30f; int i1 = 0;
#pragma unroll
    for (int j = 0; j < 8; ++j) if (j != i0 && lg[j] > m1) { m1 = lg[j]; i1 = j; }
    float eb = expf(m1 - m0), inv = 1.f / (1.f + eb);
    g0 = inv; g1 = eb * inv; e0 = i0; e1 = i1;
  }

  // lane-fixed row pointers
  const float* xr  = x + ((size_t)b * L_ + l0 + r16) * H_;     // lane's x row
  const float* w0p = ldown + ((size_t)e0 * R_ + r16) * H_;     // A-frag row r16
  const float* w1p = ldown + ((size_t)e1 * R_ + r16) * H_;

  // ---- Phase A: D^T = Wd * X^T, full K per wave; keep xf in registers -----
  bf16x8 xf[32];                            // 128 VGPRs, reused in phase B
  f32x4 acc0 = {0.f, 0.f, 0.f, 0.f};
  f32x4 acc1 = {0.f, 0.f, 0.f, 0.f};

#pragma unroll
  for (int s = 0; s < 32; ++s) {
    const int kl = s * 32 + 4 * gq;         // elems 0..3 (elems 4..7: +16)
    float4 xlo = *(const float4*)(xr + kl);
    float4 xhi = *(const float4*)(xr + kl + 16);
    float4 alo = *(const float4*)(w0p + kl);
    float4 ahi = *(const float4*)(w0p + kl + 16);
    float4 blo = *(const float4*)(w1p + kl);
    float4 bhi = *(const float4*)(w1p + kl + 16);
    bf16x8 xq  = { f2b(xlo.x), f2b(xlo.y), f2b(xlo.z), f2b(xlo.w),
                   f2b(xhi.x), f2b(xhi.y), f2b(xhi.z), f2b(xhi.w) };
    xf[s] = xq;
    bf16x8 wf0 = { f2b(alo.x), f2b(alo.y), f2b(alo.z), f2b(alo.w),
                   f2b(ahi.x), f2b(ahi.y), f2b(ahi.z), f2b(ahi.w) };
    bf16x8 wf1 = { f2b(blo.x), f2b(blo.y), f2b(blo.z), f2b(blo.w),
                   f2b(bhi.x), f2b(bhi.y), f2b(bhi.z), f2b(bhi.w) };
    acc0 = __builtin_amdgcn_mfma_f32_16x16x32_bf16(wf0, xq, acc0, 0, 0, 0);
    acc1 = __builtin_amdgcn_mfma_f32_16x16x32_bf16(wf1, xq, acc1, 0, 0, 0);
  }

  // ---- gate + pack: lane holds D[l=r16][p=4gq+j] == phase-B B-frag --------
  bf16x8 dfrag;
#pragma unroll
  for (int j = 0; j < 4; ++j) {
    dfrag[j]     = f2b(acc0[j] * g0);       // k = 4gq+j      (expert e0)
    dfrag[4 + j] = f2b(acc1[j] * g1);       // k = 16+4gq+j   (expert e1)
  }

  // ---- Phase B: out^T[h][l] = x^T + U^T(16x32) Dg^T; residual from xf -----
  const float* u0b = lup + (size_t)e0 * H_ * R_;
  const float* u1b = lup + (size_t)e1 * H_ * R_;
  float* outr = out + ((size_t)b * L_ + l0 + r16) * H_;        // lane's out row

#pragma unroll
  for (int nt = 0; nt < 64; ++nt) {
    const int ha = nt * 16 + r16;           // A-frag row (h) for this lane
    float4 ulo = *(const float4*)(u0b + (size_t)ha * R_ + 4 * gq);
    float4 uhi = *(const float4*)(u1b + (size_t)ha * R_ + 4 * gq);
    bf16x8 uf = { f2b(ulo.x), f2b(ulo.y), f2b(ulo.z), f2b(ulo.w),
                  f2b(uhi.x), f2b(uhi.y), f2b(uhi.z), f2b(uhi.w) };
    // residual: the exact quad loaded in phase A (cols nt*16+4gq..+3)
    bf16x8 xq = xf[nt >> 1];
    f32x4 acc;
    if (nt & 1) {
      acc[0] = (float)xq[4]; acc[1] = (float)xq[5];
      acc[2] = (float)xq[6]; acc[3] = (float)xq[7];
    } else {
      acc[0] = (float)xq[0]; acc[1] = (float)xq[1];
      acc[2] = (float)xq[2]; acc[3] = (float)xq[3];
    }
    acc = __builtin_amdgcn_mfma_f32_16x16x32_bf16(uf, dfrag, acc, 0, 0, 0);
    *(float4*)(outr + nt * 16 + 4 * gq) = *(float4*)&acc;
  }
}

extern "C" void kernel_launch(void* const* d_in, const int* in_sizes, int n_in,
                              void* d_out, int out_size, void* d_ws, size_t ws_size,
                              hipStream_t stream) {
  const float* x  = (const float*)d_in[0];
  const float* rw = (const float*)d_in[1];
  const float* ld = (const float*)d_in[2];
  const float* lu = (const float*)d_in[3];
  float* outp = (float*)d_out;

  hipLaunchKernelGGL(moe_fused_kernel, dim3(B_ * (L_ / 16)), dim3(64), 0,
                     stream, x, rw, ld, lu, outp);
}